// Round 1
// baseline (285.238 us; speedup 1.0000x reference)
//
#include <hip/hip_runtime.h>
#include <stdint.h>

// Problem constants (B,T,J,D) = (64, 2048, 128, 256)
#define Bb 64
#define Tt 2048
#define Jj 128
#define Dd 256

// Tile config: 128x128 output tile per block, BK=64, 4 waves (2x2), each wave
// computes 64x64 via 4x4 grid of 16x16x32 bf16 MFMAs.
#define BM 128
#define BN 128
#define BK 64
#define LDA 72   // padded LDS row stride in bf16 elems (64 + 8): 144 B rotates banks by 4/row

typedef __attribute__((ext_vector_type(8))) __bf16 bf16x8;
typedef __attribute__((ext_vector_type(8))) unsigned short ushort8v;
typedef __attribute__((ext_vector_type(4))) float f32x4;

__device__ __forceinline__ unsigned short f2bf(float f) {
    // round-to-nearest-even fp32 -> bf16 (inputs are normal randn values; no NaN handling needed)
    unsigned int u = __builtin_bit_cast(unsigned int, f);
    u += 0x7FFFu + ((u >> 16) & 1u);
    return (unsigned short)(u >> 16);
}

__global__ __launch_bounds__(256, 2)
void sim_kernel(const float* __restrict__ H, const float* __restrict__ U,
                const float* __restrict__ w, float* __restrict__ out) {
    __shared__ unsigned short lA[BM * LDA];   // (H*w3) tile, bf16
    __shared__ unsigned short lB[BN * LDA];   // U tile, bf16
    __shared__ float sh[BM];                  // H . w1 per local row
    __shared__ float su[BN];                  // U . w2 per local col

    const int tid = threadIdx.x;
    const int b = blockIdx.x >> 4;      // 16 m-tiles per batch (T/BM = 2048/128)
    const int mtile = blockIdx.x & 15;
    const int m0 = mtile * BM;

    const float* Hb = H + ((size_t)b * Tt + m0) * Dd;
    const float* Ub = U + (size_t)b * Jj * Dd;   // J == BN, single n-tile

    if (tid < BM) sh[tid] = 0.f;
    else          su[tid - BM] = 0.f;

    const int lane  = tid & 63;
    const int wid   = tid >> 6;
    const int wr    = wid >> 1;        // wave row (0..1)
    const int wc    = wid & 1;         // wave col (0..1)
    const int row16 = lane & 15;       // m/n index within a 16-tile
    const int quad  = lane >> 4;       // 0..3, selects k-octet

    f32x4 acc[4][4];
#pragma unroll
    for (int i = 0; i < 4; ++i)
#pragma unroll
        for (int j = 0; j < 4; ++j)
            acc[i][j] = (f32x4){0.f, 0.f, 0.f, 0.f};

    // staging decomposition: 256 threads -> 16 rows x 16 k-quads per pass
    const int sr = tid >> 4;       // 0..15
    const int kl = (tid & 15) * 4; // k offset within BK (float4 granules)

    for (int kb = 0; kb < Dd / BK; ++kb) {
        const int k0 = kb * BK;
        __syncthreads();   // previous MFMA done before overwriting LDS

        const float4 w1v = *(const float4*)(w + k0 + kl);
        const float4 w2v = *(const float4*)(w + Dd + k0 + kl);
        const float4 w3v = *(const float4*)(w + 2 * Dd + k0 + kl);

        // stage A = H * w3 (bf16), accumulate sh += H . w1 (fp32 exact)
#pragma unroll
        for (int p = 0; p < 8; ++p) {
            const int rr = p * 16 + sr;
            const float4 h = *(const float4*)(Hb + (size_t)rr * Dd + k0 + kl);
            atomicAdd(&sh[rr], h.x * w1v.x + h.y * w1v.y + h.z * w1v.z + h.w * w1v.w);
            ushort4 s;
            s.x = f2bf(h.x * w3v.x);
            s.y = f2bf(h.y * w3v.y);
            s.z = f2bf(h.z * w3v.z);
            s.w = f2bf(h.w * w3v.w);
            *(ushort4*)(&lA[rr * LDA + kl]) = s;
        }
        // stage B = U (bf16), accumulate su += U . w2
#pragma unroll
        for (int p = 0; p < 8; ++p) {
            const int rr = p * 16 + sr;
            const float4 u = *(const float4*)(Ub + (size_t)rr * Dd + k0 + kl);
            atomicAdd(&su[rr], u.x * w2v.x + u.y * w2v.y + u.z * w2v.z + u.w * w2v.w);
            ushort4 s;
            s.x = f2bf(u.x);
            s.y = f2bf(u.y);
            s.z = f2bf(u.z);
            s.w = f2bf(u.w);
            *(ushort4*)(&lB[rr * LDA + kl]) = s;
        }
        __syncthreads();

        // MFMA main loop: 2 k-steps of 32 per BK
#pragma unroll
        for (int ks = 0; ks < BK; ks += 32) {
            bf16x8 af[4], bfr[4];
#pragma unroll
            for (int i = 0; i < 4; ++i) {
                const int rowA = wr * 64 + i * 16 + row16;
                af[i] = __builtin_bit_cast(bf16x8,
                    *(const ushort8v*)(&lA[rowA * LDA + ks + quad * 8]));
            }
#pragma unroll
            for (int j = 0; j < 4; ++j) {
                const int rowB = wc * 64 + j * 16 + row16;
                bfr[j] = __builtin_bit_cast(bf16x8,
                    *(const ushort8v*)(&lB[rowB * LDA + ks + quad * 8]));
            }
#pragma unroll
            for (int i = 0; i < 4; ++i)
#pragma unroll
                for (int j = 0; j < 4; ++j)
                    acc[i][j] = __builtin_amdgcn_mfma_f32_16x16x32_bf16(
                        af[i], bfr[j], acc[i][j], 0, 0, 0);
        }
    }

    // epilogue: C/D layout (verified m89/m91): col = lane&15, row = quad*4 + reg
    float* outB = out + ((size_t)b * Tt + m0) * Jj;
#pragma unroll
    for (int i = 0; i < 4; ++i) {
        const int rbase = wr * 64 + i * 16 + quad * 4;
#pragma unroll
        for (int j = 0; j < 4; ++j) {
            const int col = wc * 64 + j * 16 + row16;
            const float suv = su[col];
#pragma unroll
            for (int rg = 0; rg < 4; ++rg) {
                const int rowl = rbase + rg;
                outB[(size_t)rowl * Jj + col] = acc[i][j][rg] + sh[rowl] + suv;
            }
        }
    }
}

extern "C" void kernel_launch(void* const* d_in, const int* in_sizes, int n_in,
                              void* d_out, int out_size, void* d_ws, size_t ws_size,
                              hipStream_t stream) {
    const float* H = (const float*)d_in[0];
    const float* U = (const float*)d_in[1];
    const float* w = (const float*)d_in[2];
    float* out = (float*)d_out;

    const int blocks = Bb * (Tt / BM);   // 64 * 16 = 1024
    sim_kernel<<<blocks, 256, 0, stream>>>(H, U, w, out);
}

// Round 2
// 269.624 us; speedup vs baseline: 1.0579x; 1.0579x over previous
//
#include <hip/hip_runtime.h>
#include <stdint.h>

// Problem constants (B,T,J,D) = (64, 2048, 128, 256)
#define Bb 64
#define Tt 2048
#define Jj 128
#define Dd 256

// LDS-free structure: each wave owns 64 output rows x all 128 cols.
// A (H*w3) and B (U) fragments are loaded DIRECTLY from global into MFMA
// operand layout (A[m=lane&15][k=quad*8+e]) -- no LDS, no barriers, no
// atomics. s_h/s_u accumulate per-lane and butterfly-reduce over quads.
// Block = 256 threads (4 waves) covering 256 rows; grid = 64 * 8 = 512.

typedef __attribute__((ext_vector_type(8))) __bf16 bf16x8;
typedef __attribute__((ext_vector_type(8))) unsigned short ushort8v;
typedef __attribute__((ext_vector_type(4))) float f32x4;

__device__ __forceinline__ unsigned short f2bf(float f) {
    // round-to-nearest-even fp32 -> bf16 (randn inputs; no NaN handling)
    unsigned int u = __builtin_bit_cast(unsigned int, f);
    u += 0x7FFFu + ((u >> 16) & 1u);
    return (unsigned short)(u >> 16);
}

__device__ __forceinline__ float dot8(const float4& a0, const float4& a1,
                                      const float4& b0, const float4& b1) {
    return a0.x * b0.x + a0.y * b0.y + a0.z * b0.z + a0.w * b0.w +
           a1.x * b1.x + a1.y * b1.y + a1.z * b1.z + a1.w * b1.w;
}

__device__ __forceinline__ bf16x8 pack8(const float4& a0, const float4& a1) {
    ushort8v s;
    s[0] = f2bf(a0.x); s[1] = f2bf(a0.y); s[2] = f2bf(a0.z); s[3] = f2bf(a0.w);
    s[4] = f2bf(a1.x); s[5] = f2bf(a1.y); s[6] = f2bf(a1.z); s[7] = f2bf(a1.w);
    return __builtin_bit_cast(bf16x8, s);
}

__device__ __forceinline__ bf16x8 pack8_scaled(const float4& a0, const float4& a1,
                                               const float4& s0, const float4& s1) {
    ushort8v s;
    s[0] = f2bf(a0.x * s0.x); s[1] = f2bf(a0.y * s0.y);
    s[2] = f2bf(a0.z * s0.z); s[3] = f2bf(a0.w * s0.w);
    s[4] = f2bf(a1.x * s1.x); s[5] = f2bf(a1.y * s1.y);
    s[6] = f2bf(a1.z * s1.z); s[7] = f2bf(a1.w * s1.w);
    return __builtin_bit_cast(bf16x8, s);
}

__global__ __launch_bounds__(256, 2)
void sim_kernel(const float* __restrict__ H, const float* __restrict__ U,
                const float* __restrict__ w, float* __restrict__ out) {
    const int tid   = threadIdx.x;
    const int wid   = tid >> 6;
    const int lane  = tid & 63;
    const int row16 = lane & 15;   // m (A) / n (B) index within a 16-tile
    const int quad  = lane >> 4;   // selects k-octet in operand layout

    const int b  = blockIdx.x >> 3;                      // batch
    const int m0 = (blockIdx.x & 7) * 256 + wid * 64;    // this wave's first row

    // per-lane base pointers (k-octet baked in)
    const float* Hw = H + ((size_t)b * Tt + m0 + row16) * Dd + quad * 8;
    const float* Uw = U + ((size_t)b * Jj + row16) * Dd + quad * 8;
    const float* wq = w + quad * 8;   // w1 slice; w2 at +Dd, w3 at +2*Dd

    f32x4 acc[4][8];
#pragma unroll
    for (int i = 0; i < 4; ++i)
#pragma unroll
        for (int j = 0; j < 8; ++j)
            acc[i][j] = (f32x4){0.f, 0.f, 0.f, 0.f};

    float sh[4] = {0.f, 0.f, 0.f, 0.f};
    float su[8] = {0.f, 0.f, 0.f, 0.f, 0.f, 0.f, 0.f, 0.f};

#pragma unroll 1
    for (int kb = 0; kb < Dd / 32; ++kb) {
        const int k0 = kb * 32;

        const float4 w1a = *(const float4*)(wq + k0);
        const float4 w1b = *(const float4*)(wq + k0 + 4);
        const float4 w2a = *(const float4*)(wq + Dd + k0);
        const float4 w2b = *(const float4*)(wq + Dd + k0 + 4);
        const float4 w3a = *(const float4*)(wq + 2 * Dd + k0);
        const float4 w3b = *(const float4*)(wq + 2 * Dd + k0 + 4);

        // A fragments: rows m0 + i*16 + row16, k-slice k0 + quad*8 .. +8
        bf16x8 af[4];
#pragma unroll
        for (int i = 0; i < 4; ++i) {
            const float* hp = Hw + (size_t)i * 16 * Dd + k0;
            const float4 h0 = *(const float4*)(hp);
            const float4 h1 = *(const float4*)(hp + 4);
            sh[i] += dot8(h0, h1, w1a, w1b);
            af[i] = pack8_scaled(h0, h1, w3a, w3b);
        }

        // B fragments: U rows j*16 + row16, same k-slice
        bf16x8 bfr[8];
#pragma unroll
        for (int j = 0; j < 8; ++j) {
            const float* up = Uw + (size_t)j * 16 * Dd + k0;
            const float4 u0 = *(const float4*)(up);
            const float4 u1 = *(const float4*)(up + 4);
            su[j] += dot8(u0, u1, w2a, w2b);
            bfr[j] = pack8(u0, u1);
        }

#pragma unroll
        for (int i = 0; i < 4; ++i)
#pragma unroll
            for (int j = 0; j < 8; ++j)
                acc[i][j] = __builtin_amdgcn_mfma_f32_16x16x32_bf16(
                    af[i], bfr[j], acc[i][j], 0, 0, 0);
    }

    // butterfly-reduce s_h / s_u over the 4 quads (bits 4,5 of lane id)
#pragma unroll
    for (int i = 0; i < 4; ++i) {
        sh[i] += __shfl_xor(sh[i], 16);
        sh[i] += __shfl_xor(sh[i], 32);
    }
#pragma unroll
    for (int j = 0; j < 8; ++j) {
        su[j] += __shfl_xor(su[j], 16);
        su[j] += __shfl_xor(su[j], 32);
    }

    // epilogue: C/D layout col = lane&15, row = quad*4 + reg (verified R1)
    float* outW = out + ((size_t)b * Tt + m0) * Jj;
#pragma unroll
    for (int i = 0; i < 4; ++i) {
        float shv[4];
#pragma unroll
        for (int rg = 0; rg < 4; ++rg)
            shv[rg] = __shfl(sh[i], quad * 4 + rg);  // value uniform over bits 4-5
#pragma unroll
        for (int j = 0; j < 8; ++j) {
            const int col = j * 16 + row16;
#pragma unroll
            for (int rg = 0; rg < 4; ++rg) {
                const int r = i * 16 + quad * 4 + rg;
                outW[(size_t)r * Jj + col] = acc[i][j][rg] + shv[rg] + su[j];
            }
        }
    }
}

extern "C" void kernel_launch(void* const* d_in, const int* in_sizes, int n_in,
                              void* d_out, int out_size, void* d_ws, size_t ws_size,
                              hipStream_t stream) {
    const float* H = (const float*)d_in[0];
    const float* U = (const float*)d_in[1];
    const float* w = (const float*)d_in[2];
    float* out = (float*)d_out;

    const int blocks = Bb * (Tt / 256);   // 512 blocks x 4 waves, 64 rows/wave
    sim_kernel<<<blocks, 256, 0, stream>>>(H, U, w, out);
}

// Round 3
// 247.412 us; speedup vs baseline: 1.1529x; 1.0898x over previous
//
#include <hip/hip_runtime.h>
#include <stdint.h>

// Problem constants (B,T,J,D) = (64, 2048, 128, 256)
#define Bb 64
#define Tt 2048
#define Jj 128
#define Dd 256

// Three-kernel plan:
//  prep_u : U * w3 -> bf16, stored in MFMA B-fragment lane order (U'), so the
//           main kernel's B loads are perfectly coalesced 16B/lane.
//  prep_su: s_u[b][j] = U[b][j][:] . w2   (fp32 exact)
//  main   : each wave owns 16 H-rows x all 128 cols. acc[8] = 32 VGPRs ->
//           lean enough for 4 waves/SIMD (launch_bounds(256,4)), grid 2048
//           blocks = 8 blocks/CU. H loaded fp32 in A-fragment layout, s_h via
//           in-register dot + quad butterflies. No LDS, no barriers, no atomics.

typedef __attribute__((ext_vector_type(8))) __bf16 bf16x8;
typedef __attribute__((ext_vector_type(8))) unsigned short ushort8v;
typedef __attribute__((ext_vector_type(4))) float f32x4;

__device__ __forceinline__ unsigned short f2bf(float f) {
    unsigned int u = __builtin_bit_cast(unsigned int, f);
    u += 0x7FFFu + ((u >> 16) & 1u);
    return (unsigned short)(u >> 16);
}

__device__ __forceinline__ float dot8(const float4& a0, const float4& a1,
                                      const float4& b0, const float4& b1) {
    return a0.x * b0.x + a0.y * b0.y + a0.z * b0.z + a0.w * b0.w +
           a1.x * b1.x + a1.y * b1.y + a1.z * b1.z + a1.w * b1.w;
}

__device__ __forceinline__ bf16x8 pack8(const float4& a0, const float4& a1) {
    ushort8v s;
    s[0] = f2bf(a0.x); s[1] = f2bf(a0.y); s[2] = f2bf(a0.z); s[3] = f2bf(a0.w);
    s[4] = f2bf(a1.x); s[5] = f2bf(a1.y); s[6] = f2bf(a1.z); s[7] = f2bf(a1.w);
    return __builtin_bit_cast(bf16x8, s);
}

// ---- prep 1: U' = fragment-ordered bf16(U * w3) ------------------------------
// U'[((b*8 + j)*8 + ks)*64 + lane] (16B units); lane=(quad,row16) holds
// U[b][j*16+row16][ks*32+quad*8 .. +8] * w3[...]
__global__ __launch_bounds__(256)
void prep_u(const float* __restrict__ U, const float* __restrict__ w,
            unsigned short* __restrict__ Up) {
    const int idx = blockIdx.x * 256 + threadIdx.x;   // 262144 total
    const int b  = idx >> 12;
    const int j  = (idx >> 9) & 7;
    const int ks = (idx >> 6) & 7;
    const int l  = idx & 63;
    const int row = j * 16 + (l & 15);
    const int k0  = ks * 32 + (l >> 4) * 8;

    const float* up = U + ((size_t)(b * Jj + row)) * Dd + k0;
    const float* wp = w + 2 * Dd + k0;
    const float4 u0 = *(const float4*)(up);
    const float4 u1 = *(const float4*)(up + 4);
    const float4 w0 = *(const float4*)(wp);
    const float4 w1 = *(const float4*)(wp + 4);

    ushort8v s;
    s[0] = f2bf(u0.x * w0.x); s[1] = f2bf(u0.y * w0.y);
    s[2] = f2bf(u0.z * w0.z); s[3] = f2bf(u0.w * w0.w);
    s[4] = f2bf(u1.x * w1.x); s[5] = f2bf(u1.y * w1.y);
    s[6] = f2bf(u1.z * w1.z); s[7] = f2bf(u1.w * w1.w);
    ((ushort8v*)Up)[idx] = s;   // fully coalesced 16B/thread
}

// ---- prep 2: s_u[b][j] = U[b][j][:] . w2 -------------------------------------
__global__ __launch_bounds__(128)
void prep_su(const float* __restrict__ U, const float* __restrict__ w,
             float* __restrict__ su) {
    const int b = blockIdx.x, col = threadIdx.x;
    const float* up = U + ((size_t)b * Jj + col) * Dd;
    const float* w2 = w + Dd;
    float s = 0.f;
#pragma unroll 4
    for (int d = 0; d < Dd; d += 4) {
        const float4 u = *(const float4*)(up + d);
        const float4 v = *(const float4*)(w2 + d);
        s += u.x * v.x + u.y * v.y + u.z * v.z + u.w * v.w;
    }
    su[b * Jj + col] = s;
}

// ---- main: wave = 16 rows x 128 cols ----------------------------------------
__global__ __launch_bounds__(256, 4)
void sim_main(const float* __restrict__ H, const unsigned short* __restrict__ Up,
              const float* __restrict__ w, const float* __restrict__ su,
              float* __restrict__ out) {
    const int tid   = threadIdx.x;
    const int wid   = tid >> 6;
    const int lane  = tid & 63;
    const int row16 = lane & 15;
    const int quad  = lane >> 4;

    const int b  = blockIdx.x >> 5;                     // 32 blocks per batch
    const int m0 = ((blockIdx.x & 31) * 4 + wid) * 16;  // this wave's 16-row strip

    const float* Hp = H + ((size_t)(b * Tt + m0 + row16)) * Dd + quad * 8;
    const unsigned short* Ub = Up + (size_t)b * 8 * 8 * 512;  // 32768 shorts/batch
    const float* wq = w + quad * 8;

    f32x4 acc[8];
#pragma unroll
    for (int j = 0; j < 8; ++j) acc[j] = (f32x4){0.f, 0.f, 0.f, 0.f};
    float sh = 0.f;

#pragma unroll 1
    for (int ks = 0; ks < 8; ++ks) {
        const float4 h0 = *(const float4*)(Hp + ks * 32);
        const float4 h1 = *(const float4*)(Hp + ks * 32 + 4);

        bf16x8 bfr[8];
#pragma unroll
        for (int j = 0; j < 8; ++j)
            bfr[j] = __builtin_bit_cast(bf16x8,
                *(const ushort8v*)(Ub + ((size_t)(j * 8 + ks) * 64 + lane) * 8));

        const float4 w1a = *(const float4*)(wq + ks * 32);
        const float4 w1b = *(const float4*)(wq + ks * 32 + 4);
        sh += dot8(h0, h1, w1a, w1b);

        const bf16x8 af = pack8(h0, h1);
#pragma unroll
        for (int j = 0; j < 8; ++j)
            acc[j] = __builtin_amdgcn_mfma_f32_16x16x32_bf16(af, bfr[j], acc[j], 0, 0, 0);
    }

    // reduce sh over the quad bits (4,5): all lanes of a row16 get the row sum
    sh += __shfl_xor(sh, 16);
    sh += __shfl_xor(sh, 32);
    float shv[4];
#pragma unroll
    for (int rg = 0; rg < 4; ++rg)
        shv[rg] = __shfl(sh, quad * 4 + rg);   // sh for output row quad*4+rg

    // epilogue: C/D layout col = lane&15, row = quad*4 + reg (verified R1/R2)
    float* outW = out + ((size_t)(b * Tt + m0)) * Jj;
    const float* sub = su + b * Jj;
#pragma unroll
    for (int j = 0; j < 8; ++j) {
        const int col = j * 16 + row16;
        const float suv = sub[col];
#pragma unroll
        for (int rg = 0; rg < 4; ++rg)
            outW[(size_t)(quad * 4 + rg) * Jj + col] = acc[j][rg] + shv[rg] + suv;
    }
}

extern "C" void kernel_launch(void* const* d_in, const int* in_sizes, int n_in,
                              void* d_out, int out_size, void* d_ws, size_t ws_size,
                              hipStream_t stream) {
    const float* H = (const float*)d_in[0];
    const float* U = (const float*)d_in[1];
    const float* w = (const float*)d_in[2];
    float* out = (float*)d_out;

    unsigned short* Up = (unsigned short*)d_ws;                 // 4,194,304 B
    float* su = (float*)((char*)d_ws + (size_t)Bb * Jj * Dd * 2); // + 32 KB

    prep_u<<<1024, 256, 0, stream>>>(U, w, Up);
    prep_su<<<Bb, 128, 0, stream>>>(U, w, su);
    sim_main<<<Bb * 32, 256, 0, stream>>>(H, Up, w, su, out);
}

// Round 4
// 232.708 us; speedup vs baseline: 1.2257x; 1.0632x over previous
//
#include <hip/hip_runtime.h>
#include <stdint.h>

// Problem constants (B,T,J,D) = (64, 2048, 128, 256)
#define Bb 64
#define Tt 2048
#define Jj 128
#define Dd 256

// R4 structure:
//  prep_upw1: Up' = bf16(U*w3) in MFMA B-fragment lane order, 8 j-tiles per
//             batch PLUS a 9th tile whose col 0 is bf16(w1) (rest zero) so the
//             main loop computes s_h with one extra MFMA (no w-loads in loop).
//  prep_su  : s_u[b][j] = U . w2, one wave per row (fp32 exact).
//  sim_main : block = 512 thr (8 waves), Up' tiles 0..7 staged to LDS (64 KB,
//             2 blocks/CU). Each wave owns 16 H-rows x 128 cols. H is read
//             fp32 directly in A-fragment layout with a rolling depth-4
//             register prefetch (8x1KB always in flight on the vmcnt path);
//             B-fragments come from LDS (lgkmcnt path). No atomics.

typedef __attribute__((ext_vector_type(8))) __bf16 bf16x8;
typedef __attribute__((ext_vector_type(8))) unsigned short ushort8v;
typedef __attribute__((ext_vector_type(4))) float f32x4;

__device__ __forceinline__ unsigned short f2bf(float f) {
    unsigned int u = __builtin_bit_cast(unsigned int, f);
    u += 0x7FFFu + ((u >> 16) & 1u);
    return (unsigned short)(u >> 16);
}

__device__ __forceinline__ bf16x8 pack8(const float4& a0, const float4& a1) {
    ushort8v s;
    s[0] = f2bf(a0.x); s[1] = f2bf(a0.y); s[2] = f2bf(a0.z); s[3] = f2bf(a0.w);
    s[4] = f2bf(a1.x); s[5] = f2bf(a1.y); s[6] = f2bf(a1.z); s[7] = f2bf(a1.w);
    return __builtin_bit_cast(bf16x8, s);
}

// ---- prep 1: Up' fragment tiles (9 per batch: 8 of U*w3, 1 of w1-column) ----
// unit index ((b*9 + j)*8 + ks)*64 + l ; each unit = 16 B (8 bf16)
__global__ __launch_bounds__(256)
void prep_upw1(const float* __restrict__ U, const float* __restrict__ w,
               unsigned short* __restrict__ Up) {
    const int idx = blockIdx.x * 256 + threadIdx.x;     // 64*9*512 = 294912
    const int b   = idx / 4608;
    const int rem = idx - b * 4608;
    const int j   = rem >> 9;          // 0..8
    const int ks  = (rem >> 6) & 7;
    const int l   = idx & 63;
    const int k0  = ks * 32 + (l >> 4) * 8;

    ushort8v s;
    if (j < 8) {
        const int row = j * 16 + (l & 15);
        const float* up = U + ((size_t)(b * Jj + row)) * Dd + k0;
        const float* wp = w + 2 * Dd + k0;
        const float4 u0 = *(const float4*)(up);
        const float4 u1 = *(const float4*)(up + 4);
        const float4 w0 = *(const float4*)(wp);
        const float4 w1 = *(const float4*)(wp + 4);
        s[0] = f2bf(u0.x * w0.x); s[1] = f2bf(u0.y * w0.y);
        s[2] = f2bf(u0.z * w0.z); s[3] = f2bf(u0.w * w0.w);
        s[4] = f2bf(u1.x * w1.x); s[5] = f2bf(u1.y * w1.y);
        s[6] = f2bf(u1.z * w1.z); s[7] = f2bf(u1.w * w1.w);
    } else {
        // w1-column tile: B[n][k] = (n==0) ? w1[k] : 0
        const bool n0 = (l & 15) == 0;
#pragma unroll
        for (int e = 0; e < 8; ++e)
            s[e] = n0 ? f2bf(w[k0 + e]) : (unsigned short)0;
    }
    ((ushort8v*)Up)[idx] = s;
}

// ---- prep 2: s_u[b][j] = U[b][j][:] . w2  (one wave per row) ----------------
__global__ __launch_bounds__(256)
void prep_su(const float* __restrict__ U, const float* __restrict__ w,
             float* __restrict__ su) {
    const int row  = blockIdx.x * 4 + (threadIdx.x >> 6);  // 8192 rows
    const int lane = threadIdx.x & 63;
    const float4 u = *(const float4*)(U + (size_t)row * Dd + lane * 4);
    const float4 v = *(const float4*)(w + Dd + lane * 4);
    float s = u.x * v.x + u.y * v.y + u.z * v.z + u.w * v.w;
#pragma unroll
    for (int d = 1; d < 64; d <<= 1) s += __shfl_xor(s, d);
    if (lane == 0) su[row] = s;
}

// ---- main -------------------------------------------------------------------
__global__ __launch_bounds__(512, 4)
void sim_main(const float* __restrict__ H, const unsigned short* __restrict__ Up,
              const float* __restrict__ su, float* __restrict__ out) {
    __shared__ ushort8v lUp[4096];   // 64 KB: tiles j=0..7, unit (j*8+ks)*64+lane

    const int tid   = threadIdx.x;
    const int wid   = tid >> 6;
    const int lane  = tid & 63;
    const int row16 = lane & 15;
    const int quad  = lane >> 4;

    const int b  = blockIdx.x >> 4;                      // 16 blocks per batch
    const int m0 = (blockIdx.x & 15) * 128 + wid * 16;   // this wave's 16 rows

    // stage Up' tiles 0..7 for this batch into LDS (coalesced 16B/thread)
    const ushort8v* Ub = (const ushort8v*)Up + (size_t)b * 9 * 512;
#pragma unroll
    for (int p = 0; p < 8; ++p)
        lUp[tid + p * 512] = Ub[tid + p * 512];

    // w1-column fragments (tile 8), register-resident for the whole loop
    bf16x8 w1f[8];
    const ushort8v* Uw1 = Ub + 8 * 512 + lane;
#pragma unroll
    for (int ks = 0; ks < 8; ++ks)
        w1f[ks] = __builtin_bit_cast(bf16x8, Uw1[ks * 64]);

    // rolling depth-4 H prefetch (A-fragment layout: lane holds row m0+row16,
    // k-octet quad*8, slices of 32 along k)
    const float* Hp = H + ((size_t)(b * Tt + m0 + row16)) * Dd + quad * 8;
    float4 hb0[4], hb1[4];
#pragma unroll
    for (int p = 0; p < 4; ++p) {
        hb0[p] = *(const float4*)(Hp + p * 32);
        hb1[p] = *(const float4*)(Hp + p * 32 + 4);
    }

    f32x4 acc[8];
#pragma unroll
    for (int j = 0; j < 8; ++j) acc[j] = (f32x4){0.f, 0.f, 0.f, 0.f};
    f32x4 accW = (f32x4){0.f, 0.f, 0.f, 0.f};

    __syncthreads();

#pragma unroll
    for (int ks = 0; ks < 8; ++ks) {
        const int slot = ks & 3;
        const float4 h0 = hb0[slot];
        const float4 h1 = hb1[slot];
        if (ks < 4) {   // static (loop fully unrolled): refill the slot
            hb0[slot] = *(const float4*)(Hp + (ks + 4) * 32);
            hb1[slot] = *(const float4*)(Hp + (ks + 4) * 32 + 4);
        }

        bf16x8 bfr[8];
#pragma unroll
        for (int j = 0; j < 8; ++j)
            bfr[j] = __builtin_bit_cast(bf16x8, lUp[(j * 8 + ks) * 64 + lane]);

        const bf16x8 af = pack8(h0, h1);
#pragma unroll
        for (int j = 0; j < 8; ++j)
            acc[j] = __builtin_amdgcn_mfma_f32_16x16x32_bf16(af, bfr[j], acc[j], 0, 0, 0);
        accW = __builtin_amdgcn_mfma_f32_16x16x32_bf16(af, w1f[ks], accW, 0, 0, 0);
    }

    // s_h for output row quad*4+rg lives in lane quad*16 (col 0), reg rg
    float shv[4];
#pragma unroll
    for (int rg = 0; rg < 4; ++rg)
        shv[rg] = __shfl(accW[rg], quad * 16);

    // epilogue: C/D layout col = lane&15, row = quad*4 + reg (verified R1-R3)
    float* outW = out + ((size_t)(b * Tt + m0)) * Jj;
    const float* sub = su + b * Jj;
#pragma unroll
    for (int j = 0; j < 8; ++j) {
        const int col = j * 16 + row16;
        const float suv = sub[col];
#pragma unroll
        for (int rg = 0; rg < 4; ++rg)
            outW[(size_t)(quad * 4 + rg) * Jj + col] = acc[j][rg] + shv[rg] + suv;
    }
}

extern "C" void kernel_launch(void* const* d_in, const int* in_sizes, int n_in,
                              void* d_out, int out_size, void* d_ws, size_t ws_size,
                              hipStream_t stream) {
    const float* H = (const float*)d_in[0];
    const float* U = (const float*)d_in[1];
    const float* w = (const float*)d_in[2];
    float* out = (float*)d_out;

    unsigned short* Up = (unsigned short*)d_ws;            // 64*9*512*16 B = 4718592
    float* su = (float*)((char*)d_ws + (size_t)Bb * 9 * 512 * 16); // + 32 KB

    prep_upw1<<<1152, 256, 0, stream>>>(U, w, Up);
    prep_su<<<Bb * Jj / 4, 256, 0, stream>>>(U, w, su);
    sim_main<<<Bb * 16, 512, 0, stream>>>(H, Up, su, out);
}

// Round 5
// 229.618 us; speedup vs baseline: 1.2422x; 1.0135x over previous
//
#include <hip/hip_runtime.h>
#include <stdint.h>

// Problem constants (B,T,J,D) = (64, 2048, 128, 256)
#define Bb 64
#define Tt 2048
#define Jj 128
#define Dd 256

// R5 structure (R4 + two fixes):
//  - sim_main: __launch_bounds__(512) ONLY. R4's (512,4) capped unified regs
//    at 128 < ~146 live -> spilled the prefetch buffers (R2 failure mode
//    redux). Occupancy is LDS-limited to 2 blocks/CU (16 waves) regardless,
//    so the min-waves constraint bought nothing and cost the prefetch.
//  - preps fused into one dispatch (blockIdx-range branch).
// Everything else identical to R4: Up' = bf16(U*w3) in B-fragment lane order
// (8 j-tiles + 9th w1-column tile for s_h-via-MFMA), staged to LDS once per
// block; H read fp32 directly in A-fragment layout with rolling depth-4
// register prefetch; s_u precomputed fp32-exact.

typedef __attribute__((ext_vector_type(8))) __bf16 bf16x8;
typedef __attribute__((ext_vector_type(8))) unsigned short ushort8v;
typedef __attribute__((ext_vector_type(4))) float f32x4;

__device__ __forceinline__ unsigned short f2bf(float f) {
    unsigned int u = __builtin_bit_cast(unsigned int, f);
    u += 0x7FFFu + ((u >> 16) & 1u);
    return (unsigned short)(u >> 16);
}

__device__ __forceinline__ bf16x8 pack8(const float4& a0, const float4& a1) {
    ushort8v s;
    s[0] = f2bf(a0.x); s[1] = f2bf(a0.y); s[2] = f2bf(a0.z); s[3] = f2bf(a0.w);
    s[4] = f2bf(a1.x); s[5] = f2bf(a1.y); s[6] = f2bf(a1.z); s[7] = f2bf(a1.w);
    return __builtin_bit_cast(bf16x8, s);
}

// ---- fused prep: blocks 0..1151 build Up' (+w1 tile); 1152..3199 build s_u --
// Up' unit index ((b*9 + j)*8 + ks)*64 + l ; each unit = 16 B (8 bf16)
__global__ __launch_bounds__(256)
void prep_all(const float* __restrict__ U, const float* __restrict__ w,
              unsigned short* __restrict__ Up, float* __restrict__ su) {
    const int bid = blockIdx.x;
    const int tid = threadIdx.x;
    if (bid < 1152) {
        const int idx = bid * 256 + tid;               // 64*9*512 = 294912
        const int b   = idx / 4608;
        const int rem = idx - b * 4608;
        const int j   = rem >> 9;          // 0..8
        const int ks  = (rem >> 6) & 7;
        const int l   = idx & 63;
        const int k0  = ks * 32 + (l >> 4) * 8;

        ushort8v s;
        if (j < 8) {
            const int row = j * 16 + (l & 15);
            const float* up = U + ((size_t)(b * Jj + row)) * Dd + k0;
            const float* wp = w + 2 * Dd + k0;
            const float4 u0 = *(const float4*)(up);
            const float4 u1 = *(const float4*)(up + 4);
            const float4 w0 = *(const float4*)(wp);
            const float4 w1 = *(const float4*)(wp + 4);
            s[0] = f2bf(u0.x * w0.x); s[1] = f2bf(u0.y * w0.y);
            s[2] = f2bf(u0.z * w0.z); s[3] = f2bf(u0.w * w0.w);
            s[4] = f2bf(u1.x * w1.x); s[5] = f2bf(u1.y * w1.y);
            s[6] = f2bf(u1.z * w1.z); s[7] = f2bf(u1.w * w1.w);
        } else {
            // w1-column tile: B[n][k] = (n==0) ? w1[k] : 0
            const bool n0 = (l & 15) == 0;
#pragma unroll
            for (int e = 0; e < 8; ++e)
                s[e] = n0 ? f2bf(w[k0 + e]) : (unsigned short)0;
        }
        ((ushort8v*)Up)[idx] = s;
    } else {
        // s_u[row] = U[row][:] . w2, one wave per row
        const int row  = (bid - 1152) * 4 + (tid >> 6);    // 8192 rows
        const int lane = tid & 63;
        const float4 u = *(const float4*)(U + (size_t)row * Dd + lane * 4);
        const float4 v = *(const float4*)(w + Dd + lane * 4);
        float s = u.x * v.x + u.y * v.y + u.z * v.z + u.w * v.w;
#pragma unroll
        for (int d = 1; d < 64; d <<= 1) s += __shfl_xor(s, d);
        if (lane == 0) su[row] = s;
    }
}

// ---- main -------------------------------------------------------------------
__global__ __launch_bounds__(512)
void sim_main(const float* __restrict__ H, const unsigned short* __restrict__ Up,
              const float* __restrict__ su, float* __restrict__ out) {
    __shared__ ushort8v lUp[4096];   // 64 KB: tiles j=0..7, unit (j*8+ks)*64+lane

    const int tid   = threadIdx.x;
    const int wid   = tid >> 6;
    const int lane  = tid & 63;
    const int row16 = lane & 15;
    const int quad  = lane >> 4;

    const int b  = blockIdx.x >> 4;                      // 16 blocks per batch
    const int m0 = (blockIdx.x & 15) * 128 + wid * 16;   // this wave's 16 rows

    // stage Up' tiles 0..7 for this batch into LDS (coalesced 16B/thread)
    const ushort8v* Ub = (const ushort8v*)Up + (size_t)b * 9 * 512;
#pragma unroll
    for (int p = 0; p < 8; ++p)
        lUp[tid + p * 512] = Ub[tid + p * 512];

    // w1-column fragments (tile 8), register-resident for the whole loop
    bf16x8 w1f[8];
    const ushort8v* Uw1 = Ub + 8 * 512 + lane;
#pragma unroll
    for (int ks = 0; ks < 8; ++ks)
        w1f[ks] = __builtin_bit_cast(bf16x8, Uw1[ks * 64]);

    // rolling depth-4 H prefetch (A-fragment layout: lane holds row m0+row16,
    // k-octet quad*8, slices of 32 along k)
    const float* Hp = H + ((size_t)(b * Tt + m0 + row16)) * Dd + quad * 8;
    float4 hb0[4], hb1[4];
#pragma unroll
    for (int p = 0; p < 4; ++p) {
        hb0[p] = *(const float4*)(Hp + p * 32);
        hb1[p] = *(const float4*)(Hp + p * 32 + 4);
    }

    f32x4 acc[8];
#pragma unroll
    for (int j = 0; j < 8; ++j) acc[j] = (f32x4){0.f, 0.f, 0.f, 0.f};
    f32x4 accW = (f32x4){0.f, 0.f, 0.f, 0.f};

    __syncthreads();

#pragma unroll
    for (int ks = 0; ks < 8; ++ks) {
        const int slot = ks & 3;
        const float4 h0 = hb0[slot];
        const float4 h1 = hb1[slot];
        if (ks < 4) {   // static (loop fully unrolled): refill the slot
            hb0[slot] = *(const float4*)(Hp + (ks + 4) * 32);
            hb1[slot] = *(const float4*)(Hp + (ks + 4) * 32 + 4);
        }

        bf16x8 bfr[8];
#pragma unroll
        for (int j = 0; j < 8; ++j)
            bfr[j] = __builtin_bit_cast(bf16x8, lUp[(j * 8 + ks) * 64 + lane]);

        const bf16x8 af = pack8(h0, h1);
#pragma unroll
        for (int j = 0; j < 8; ++j)
            acc[j] = __builtin_amdgcn_mfma_f32_16x16x32_bf16(af, bfr[j], acc[j], 0, 0, 0);
        accW = __builtin_amdgcn_mfma_f32_16x16x32_bf16(af, w1f[ks], accW, 0, 0, 0);
    }

    // s_h for output row quad*4+rg lives in lane quad*16 (col 0), reg rg
    float shv[4];
#pragma unroll
    for (int rg = 0; rg < 4; ++rg)
        shv[rg] = __shfl(accW[rg], quad * 16);

    // epilogue: C/D layout col = lane&15, row = quad*4 + reg (verified R1-R4)
    float* outW = out + ((size_t)(b * Tt + m0)) * Jj;
    const float* sub = su + b * Jj;
#pragma unroll
    for (int j = 0; j < 8; ++j) {
        const int col = j * 16 + row16;
        const float suv = sub[col];
#pragma unroll
        for (int rg = 0; rg < 4; ++rg)
            outW[(size_t)(quad * 4 + rg) * Jj + col] = acc[j][rg] + shv[rg] + suv;
    }
}

extern "C" void kernel_launch(void* const* d_in, const int* in_sizes, int n_in,
                              void* d_out, int out_size, void* d_ws, size_t ws_size,
                              hipStream_t stream) {
    const float* H = (const float*)d_in[0];
    const float* U = (const float*)d_in[1];
    const float* w = (const float*)d_in[2];
    float* out = (float*)d_out;

    unsigned short* Up = (unsigned short*)d_ws;            // 64*9*512*16 B = 4718592
    float* su = (float*)((char*)d_ws + (size_t)Bb * 9 * 512 * 16); // + 32 KB

    prep_all<<<3200, 256, 0, stream>>>(U, w, Up, su);
    sim_main<<<Bb * 16, 512, 0, stream>>>(H, Up, su, out);
}